// Round 3
// baseline (456.055 us; speedup 1.0000x reference)
//
#include <hip/hip_runtime.h>
#include <hip/hip_bf16.h>

// LightAttention: Z = softmax_n(Q/d4) @ [ softmax_n(K/d4)^T @ V ]
// Folded: E=exp(Q/d4), F=exp(K/d4), Sq/Sk col-sums over n,
//   Bm[d,e] = sum_n F[n,d] V[n,e];  Ct[e,d] = Bm[d,e]/(Sq[d]Sk[d]);  Z = E @ Ct^T.
//
// Round-3 structure:
//  - conv_kernel: fp32 X -> bf16 Xb staged IN d_out (dead until final z_gemm).
//  - proj_kernel: pure m97-style loop (global_load_lds both operands, 16KB LDS).
//    z=0: A=Xq rows, B=Wq rows -> Eq[n][d] + fused Sq colsum.
//    z=1: OPERANDS SWAPPED: A=Wk rows (d), B=Xk rows (n) -> C is already [d][n],
//         direct store of Ft (no LDS transpose). z=2 same for Vt.
//  - sk_kernel: Sk[d] = row-sum of Ft (coalesced, ~6us).
//  - bm_gemm: Ft x Vt -> Bmp split-K=2 (no atomics).  scale -> Ct.  z_gemm -> out.

typedef __bf16 bf16_t;
typedef __attribute__((ext_vector_type(8))) __bf16 bf16x8;
typedef __attribute__((ext_vector_type(4))) float f32x4;

#define MFMA_BF16 __builtin_amdgcn_mfma_f32_16x16x32_bf16

__device__ inline void async_ld16(const void* g, void* l) {
  __builtin_amdgcn_global_load_lds(
      (const __attribute__((address_space(1))) void*)g,
      (__attribute__((address_space(3))) void*)l, 16, 0, 0);
}

#define INV_D4 0.2102241038134287f  // 1 / 512^0.25

// ---------------- W transpose+convert: W[in][out] f32 -> Wt[out][in] bf16 ----
__global__ __launch_bounds__(256) void wt_kernel(
    const float* __restrict__ Wq, const float* __restrict__ Wk,
    const float* __restrict__ Wv, bf16_t* __restrict__ Wt) {
  const int z = blockIdx.z;
  const float* W = (z == 0) ? Wq : (z == 1) ? Wk : Wv;
  bf16_t* O = Wt + (size_t)z * 262144;
  __shared__ __align__(16) bf16_t tile[64 * 72];
  const int t = threadIdx.x;
  const int r = t >> 2;
  const int c4 = (t & 3) * 16;
  const int in0 = blockIdx.x * 64, out0 = blockIdx.y * 64;
  const float* src = W + (size_t)(in0 + r) * 512 + out0 + c4;
#pragma unroll
  for (int i = 0; i < 4; ++i) {
    float4 f = ((const float4*)src)[i];
    tile[(c4 + i * 4 + 0) * 72 + r] = (__bf16)f.x;
    tile[(c4 + i * 4 + 1) * 72 + r] = (__bf16)f.y;
    tile[(c4 + i * 4 + 2) * 72 + r] = (__bf16)f.z;
    tile[(c4 + i * 4 + 3) * 72 + r] = (__bf16)f.w;
  }
  __syncthreads();
  bf16x8* dst = (bf16x8*)(O + (size_t)(out0 + r) * 512 + in0 + c4);
  const bf16x8* s = (const bf16x8*)(tile + r * 72 + c4);
  dst[0] = s[0];
  dst[1] = s[1];
}

// ---------------- fp32 -> bf16 streaming convert (8 elems/thread) -----------
__global__ __launch_bounds__(256) void conv_kernel(
    const float* __restrict__ a, const float* __restrict__ b,
    bf16_t* __restrict__ oa, bf16_t* __restrict__ ob) {
  const float* src = (blockIdx.z == 0) ? a : b;
  bf16_t* dst = (blockIdx.z == 0) ? oa : ob;
  const size_t i = ((size_t)blockIdx.x * 256 + threadIdx.x) * 8;
  float4 f0 = ((const float4*)(src + i))[0];
  float4 f1 = ((const float4*)(src + i))[1];
  bf16x8 p;
  p[0] = (__bf16)f0.x; p[1] = (__bf16)f0.y; p[2] = (__bf16)f0.z; p[3] = (__bf16)f0.w;
  p[4] = (__bf16)f1.x; p[5] = (__bf16)f1.y; p[6] = (__bf16)f1.z; p[7] = (__bf16)f1.w;
  *(bf16x8*)(dst + i) = p;
}

// ---------------- Projection GEMM, pure async staging -----------------------
// z = blockIdx.z + zoff.
// z==0: A=Xq rows m0 (k contiguous), B=Wq rows w0 -> Eq[n][d], Sq colsum.
// z==1: A=Wk rows w0 (d), B=Xk rows m0 (n) -> Ft[b][d][n] = exp, direct store.
// z==2: A=Wv, B=Xv -> Vt[b][e][n], direct store.
__global__ __launch_bounds__(256, 2) void proj_kernel(
    const bf16_t* __restrict__ Xa, const bf16_t* __restrict__ Xb_,
    const bf16_t* __restrict__ Wt, const float* __restrict__ biasa,
    const float* __restrict__ biasb, bf16_t* __restrict__ Eq,
    bf16_t* __restrict__ Fo, bf16_t* __restrict__ Vo, float* __restrict__ Sq,
    int zoff) {
  const int z = blockIdx.z + zoff;
  const bf16_t* X = (z == 1) ? Xb_ : Xa;
  const float* bias = (z == 1) ? biasb : biasa;
  const bf16_t* W = Wt + (size_t)z * 262144;

  __shared__ __align__(16) bf16_t As[4096];
  __shared__ __align__(16) bf16_t Bs[4096];

  const int t = threadIdx.x;
  const int lane = t & 63, w = t >> 6;
  const int quad = lane >> 4, l15 = lane & 15;
  const int m0 = blockIdx.x * 128;   // X row tile (global n over 32768)
  const int w0 = blockIdx.y * 128;   // Wt row tile (d over 512)
  const int m_off = (w & 1) * 64, n_off = (w >> 1) * 64;

  const bf16_t* Abase = (z == 0) ? X + (size_t)m0 * 512 : W + (size_t)w0 * 512;
  const bf16_t* Bbase = (z == 0) ? W + (size_t)w0 * 512 : X + (size_t)m0 * 512;

  f32x4 acc[4][4];
  const f32x4 zero4 = {0.f, 0.f, 0.f, 0.f};
#pragma unroll
  for (int i = 0; i < 4; ++i)
#pragma unroll
    for (int j = 0; j < 4; ++j) acc[i][j] = zero4;

  for (int ks = 0; ks < 16; ++ks) {
    const int k0 = ks * 32;
#pragma unroll
    for (int i = 0; i < 2; ++i) {
      const int j = w * 2 + i;
      const int k8 = j >> 1;
      const int r = ((j & 1) << 6) + lane;
      async_ld16(Abase + (size_t)r * 512 + k0 + k8 * 8, As + j * 512);
      async_ld16(Bbase + (size_t)r * 512 + k0 + k8 * 8, Bs + j * 512);
    }
    __syncthreads();
    bf16x8 af[4], bfr[4];
#pragma unroll
    for (int mi = 0; mi < 4; ++mi)
      af[mi] = ((const bf16x8*)As)[quad * 128 + m_off + mi * 16 + l15];
#pragma unroll
    for (int ni = 0; ni < 4; ++ni)
      bfr[ni] = ((const bf16x8*)Bs)[quad * 128 + n_off + ni * 16 + l15];
#pragma unroll
    for (int mi = 0; mi < 4; ++mi)
#pragma unroll
      for (int ni = 0; ni < 4; ++ni)
        acc[mi][ni] = MFMA_BF16(af[mi], bfr[ni], acc[mi][ni], 0, 0, 0);
    __syncthreads();
  }

  const int b = m0 >> 12;  // batch
  if (z == 0) {
    // C rows = X rows (n), C cols = d. Normal store + Sq colsum.
    float cs[4] = {0.f, 0.f, 0.f, 0.f};
#pragma unroll
    for (int ni = 0; ni < 4; ++ni) {
      const int col = w0 + n_off + ni * 16 + l15;
      const float bv_ = bias[col];
#pragma unroll
      for (int mi = 0; mi < 4; ++mi)
#pragma unroll
        for (int r = 0; r < 4; ++r) {
          const int row = m0 + m_off + mi * 16 + quad * 4 + r;
          float v = __expf((acc[mi][ni][r] + bv_) * INV_D4);
          Eq[(size_t)row * 512 + col] = (bf16_t)v;
          cs[ni] += v;
        }
    }
#pragma unroll
    for (int ni = 0; ni < 4; ++ni) {
      cs[ni] += __shfl_xor(cs[ni], 16);
      cs[ni] += __shfl_xor(cs[ni], 32);
    }
    if (lane < 16) {
#pragma unroll
      for (int ni = 0; ni < 4; ++ni)
        atomicAdd(&Sq[b * 512 + w0 + n_off + ni * 16 + lane], cs[ni]);
    }
  } else {
    // C rows = d, C cols = n. Output already transposed: direct store.
    const bool expm = (z == 1);
    bf16_t* Out = expm ? Fo : Vo;
    const int nl0 = (m0 & 4095) + n_off;
#pragma unroll
    for (int mi = 0; mi < 4; ++mi)
#pragma unroll
      for (int r = 0; r < 4; ++r) {
        const int d = w0 + m_off + mi * 16 + quad * 4 + r;
        const float bv_ = bias[d];
        bf16_t* rowp = Out + (size_t)b * 2097152 + (size_t)d * 4096 + nl0;
#pragma unroll
        for (int ni = 0; ni < 4; ++ni) {
          float v = acc[mi][ni][r] + bv_;
          if (expm) v = __expf(v * INV_D4);
          rowp[ni * 16 + l15] = (bf16_t)v;
        }
      }
  }
}

// ---------------- Sk[b*512+d] = sum_n Ft[b][d][n] (row sums) ----------------
__global__ __launch_bounds__(256) void sk_kernel(const bf16_t* __restrict__ Ft,
                                                 float* __restrict__ Sk) {
  const int row = blockIdx.x * 4 + (threadIdx.x >> 6);
  const int lane = threadIdx.x & 63;
  const bf16x8* p = (const bf16x8*)(Ft + (size_t)row * 4096) + lane;
  float s = 0.f;
#pragma unroll
  for (int j = 0; j < 8; ++j) {
    bf16x8 v = p[j * 64];
#pragma unroll
    for (int e = 0; e < 8; ++e) s += (float)v[e];
  }
#pragma unroll
  for (int m = 1; m <= 32; m <<= 1) s += __shfl_xor(s, m);
  if (lane == 0) Sk[row] = s;
}

// ---------------- Bm GEMM: Bmp[s][b][d][e] = sum_{n in slice} Ft[d][n]Vt[e][n]
__global__ __launch_bounds__(256, 2) void bm_gemm(
    const bf16_t* __restrict__ Ft, const bf16_t* __restrict__ Vt,
    float* __restrict__ Bmp) {
  const int b = blockIdx.z >> 1;
  const int s = blockIdx.z & 1;
  const int d0 = blockIdx.x * 128;
  const int e0 = blockIdx.y * 128;
  const bf16_t* A = Ft + (size_t)b * 2097152;
  const bf16_t* B = Vt + (size_t)b * 2097152;
  float* out = Bmp + ((size_t)s * 8 + b) * 262144;

  __shared__ __align__(16) bf16_t As[4096];
  __shared__ __align__(16) bf16_t Bs[4096];

  const int t = threadIdx.x;
  const int lane = t & 63, w = t >> 6;
  const int quad = lane >> 4, l15 = lane & 15;
  const int m_off = (w & 1) * 64, n_off = (w >> 1) * 64;

  f32x4 acc[4][4];
  const f32x4 zero4 = {0.f, 0.f, 0.f, 0.f};
#pragma unroll
  for (int i = 0; i < 4; ++i)
#pragma unroll
    for (int j = 0; j < 4; ++j) acc[i][j] = zero4;

  for (int ks = 0; ks < 64; ++ks) {
    const int k0 = s * 2048 + ks * 32;
#pragma unroll
    for (int i = 0; i < 2; ++i) {
      const int j = w * 2 + i;
      const int k8 = j >> 1;
      const int r = ((j & 1) << 6) + lane;
      async_ld16(A + (size_t)(d0 + r) * 4096 + k0 + k8 * 8, As + j * 512);
      async_ld16(B + (size_t)(e0 + r) * 4096 + k0 + k8 * 8, Bs + j * 512);
    }
    __syncthreads();
    bf16x8 af[4], bfr[4];
#pragma unroll
    for (int mi = 0; mi < 4; ++mi)
      af[mi] = ((const bf16x8*)As)[quad * 128 + m_off + mi * 16 + l15];
#pragma unroll
    for (int ni = 0; ni < 4; ++ni)
      bfr[ni] = ((const bf16x8*)Bs)[quad * 128 + n_off + ni * 16 + l15];
#pragma unroll
    for (int mi = 0; mi < 4; ++mi)
#pragma unroll
      for (int ni = 0; ni < 4; ++ni)
        acc[mi][ni] = MFMA_BF16(af[mi], bfr[ni], acc[mi][ni], 0, 0, 0);
    __syncthreads();
  }

#pragma unroll
  for (int mi = 0; mi < 4; ++mi)
#pragma unroll
    for (int ni = 0; ni < 4; ++ni) {
      const int ecol = e0 + n_off + ni * 16 + l15;
#pragma unroll
      for (int r = 0; r < 4; ++r) {
        const int drow = d0 + m_off + mi * 16 + quad * 4 + r;
        out[(size_t)drow * 512 + ecol] = acc[mi][ni][r];
      }
    }
}

// ---------------- scale + reduce partials + transpose -----------------------
// Ct[b][e][d] = (Bmp0+Bmp1)[b][d][e] / (Sq[b][d]*Sk[b][d])
__global__ __launch_bounds__(256) void scale_kernel(
    const float* __restrict__ Bmp, const float* __restrict__ Sq,
    const float* __restrict__ Sk, bf16_t* __restrict__ Ct) {
  const int b = blockIdx.z;
  const int d0 = blockIdx.x * 64, e0 = blockIdx.y * 64;
  __shared__ __align__(16) bf16_t tile[64 * 72];
  const int t = threadIdx.x;
  const int r = t >> 2;
  const int c4 = (t & 3) * 16;
  const int d = d0 + r;
  const float f = 1.0f / (Sq[b * 512 + d] * Sk[b * 512 + d]);
  const float* p0 = Bmp + (size_t)b * 262144 + (size_t)d * 512 + e0 + c4;
  const float* p1 = p0 + 2097152;
#pragma unroll
  for (int i = 0; i < 4; ++i) {
    float4 v0 = ((const float4*)p0)[i];
    float4 v1 = ((const float4*)p1)[i];
    tile[(c4 + i * 4 + 0) * 72 + r] = (__bf16)((v0.x + v1.x) * f);
    tile[(c4 + i * 4 + 1) * 72 + r] = (__bf16)((v0.y + v1.y) * f);
    tile[(c4 + i * 4 + 2) * 72 + r] = (__bf16)((v0.z + v1.z) * f);
    tile[(c4 + i * 4 + 3) * 72 + r] = (__bf16)((v0.w + v1.w) * f);
  }
  __syncthreads();
  bf16x8* dst = (bf16x8*)(Ct + (size_t)b * 262144 + (size_t)(e0 + r) * 512 + d0 + c4);
  const bf16x8* s = (const bf16x8*)(tile + r * 72 + c4);
  dst[0] = s[0];
  dst[1] = s[1];
}

// ---------------- Z GEMM: Z[row,e] = sum_d E[row,d] * Ct[b][e][d] -----------
__global__ __launch_bounds__(256, 2) void z_gemm(
    const bf16_t* __restrict__ Eq, const bf16_t* __restrict__ Ct,
    float* __restrict__ out) {
  __shared__ __align__(16) bf16_t As[4096];
  __shared__ __align__(16) bf16_t Bs[4096];

  const int t = threadIdx.x;
  const int lane = t & 63, w = t >> 6;
  const int quad = lane >> 4, l15 = lane & 15;
  const int m0 = blockIdx.x * 128;
  const int n0 = blockIdx.y * 128;
  const int batch = m0 >> 12;
  const bf16_t* Bt = Ct + (size_t)batch * 262144;
  const int m_off = (w & 1) * 64, n_off = (w >> 1) * 64;

  f32x4 acc[4][4];
  const f32x4 zero4 = {0.f, 0.f, 0.f, 0.f};
#pragma unroll
  for (int i = 0; i < 4; ++i)
#pragma unroll
    for (int j = 0; j < 4; ++j) acc[i][j] = zero4;

  for (int ks = 0; ks < 16; ++ks) {
    const int k0 = ks * 32;
#pragma unroll
    for (int i = 0; i < 2; ++i) {
      const int j = w * 2 + i;
      const int k8 = j >> 1;
      const int r = ((j & 1) << 6) + lane;
      async_ld16(Eq + (size_t)(m0 + r) * 512 + k0 + k8 * 8, As + j * 512);
      async_ld16(Bt + (size_t)(n0 + r) * 512 + k0 + k8 * 8, Bs + j * 512);
    }
    __syncthreads();
    bf16x8 af[4], bfr[4];
#pragma unroll
    for (int mi = 0; mi < 4; ++mi)
      af[mi] = ((const bf16x8*)As)[quad * 128 + m_off + mi * 16 + l15];
#pragma unroll
    for (int ni = 0; ni < 4; ++ni)
      bfr[ni] = ((const bf16x8*)Bs)[quad * 128 + n_off + ni * 16 + l15];
#pragma unroll
    for (int mi = 0; mi < 4; ++mi)
#pragma unroll
      for (int ni = 0; ni < 4; ++ni)
        acc[mi][ni] = MFMA_BF16(af[mi], bfr[ni], acc[mi][ni], 0, 0, 0);
    __syncthreads();
  }

#pragma unroll
  for (int mi = 0; mi < 4; ++mi)
#pragma unroll
    for (int ni = 0; ni < 4; ++ni) {
      const int col = n0 + n_off + ni * 16 + l15;
#pragma unroll
      for (int r = 0; r < 4; ++r) {
        const int row = m0 + m_off + mi * 16 + quad * 4 + r;
        out[(size_t)row * 512 + col] = acc[mi][ni][r];
      }
    }
}

extern "C" void kernel_launch(void* const* d_in, const int* in_sizes, int n_in,
                              void* d_out, int out_size, void* d_ws,
                              size_t ws_size, hipStream_t stream) {
  const float* xq = (const float*)d_in[0];
  const float* xk = (const float*)d_in[1];
  const float* xv = (const float*)d_in[2];
  const float* Wq = (const float*)d_in[3];
  const float* bq = (const float*)d_in[4];
  const float* Wk = (const float*)d_in[5];
  const float* bk = (const float*)d_in[6];
  const float* Wv = (const float*)d_in[7];
  const float* bv = (const float*)d_in[8];
  float* out = (float*)d_out;

  char* ws = (char*)d_ws;
  bf16_t* Eq = (bf16_t*)(ws + 0);           // 8x4096x512 bf16  33,554,432 B
  bf16_t* Ft = (bf16_t*)(ws + 33554432);    // 8x512x4096 bf16 (F transposed)
  bf16_t* Vt = (bf16_t*)(ws + 67108864);    // 8x512x4096 bf16 (V transposed)
  float* Bmp = (float*)(ws + 100663296);    // 2 x 8x512x512 f32 split-K partials
  bf16_t* Wt = (bf16_t*)(ws + 117440512);   // 3x512x512 bf16
  float* Sq = (float*)(ws + 119013376);     // 8x512 f32
  float* Sk = (float*)(ws + 119029760);     // 8x512 f32; end = 119,046,144
  bf16_t* Ct = (bf16_t*)(ws + 33554432);    // aliases Ft (dead after bm_gemm)

  // bf16 X staging lives in d_out (64MB; z_gemm overwrites it at the end)
  bf16_t* Xqb = (bf16_t*)d_out;             // 32MB
  bf16_t* Xkb = (bf16_t*)((char*)d_out + 33554432);
  bf16_t* Xvb = (bf16_t*)d_out;             // reuses Xq slot after proj(Q,K)

  hipMemsetAsync(Sq, 0, 16384, stream);  // Sq atomic target only

  wt_kernel<<<dim3(8, 8, 3), 256, 0, stream>>>(Wq, Wk, Wv, Wt);
  conv_kernel<<<dim3(8192, 1, 2), 256, 0, stream>>>(xq, xk, Xqb, Xkb);
  proj_kernel<<<dim3(256, 4, 2), 256, 0, stream>>>(Xqb, Xkb, Wt, bq, bk, Eq, Ft,
                                                   Vt, Sq, 0);
  conv_kernel<<<dim3(8192, 1, 1), 256, 0, stream>>>(xv, xv, Xvb, Xvb);
  proj_kernel<<<dim3(256, 4, 1), 256, 0, stream>>>(Xvb, Xvb, Wt, bv, bv, Eq, Ft,
                                                   Vt, Sq, 2);
  sk_kernel<<<dim3(1024), 256, 0, stream>>>(Ft, Sk);
  bm_gemm<<<dim3(4, 4, 16), 256, 0, stream>>>(Ft, Vt, Bmp);
  scale_kernel<<<dim3(8, 8, 8), 256, 0, stream>>>(Bmp, Sq, Sk, Ct);
  z_gemm<<<dim3(256, 4, 1), 256, 0, stream>>>(Eq, Ct, out);
}

// Round 4
// 387.601 us; speedup vs baseline: 1.1766x; 1.1766x over previous
//
#include <hip/hip_runtime.h>
#include <hip/hip_bf16.h>

// LightAttention: Z = softmax_n(Q/d4) @ [ softmax_n(K/d4)^T @ V ]
// Folded: E=exp(Q/d4), F=exp(K/d4), Sq/Sk col-sums over n,
//   Bm[d,e] = sum_n F[n,d] V[n,e];  Ct[e,d] = Bm[d,e]/(Sq[d]Sk[d]);  Z = E @ Ct^T.
//
// Round-4 structure:
//  - NO fp32->bf16 pre-pass: X is converted in-loop (reg prefetch, round-2
//    pattern) on the 128-row operand; W / Eq / Ct staged via global_load_lds.
//  - Wide tiles: proj_q & z_gemm = 128(m)x256(n); proj_kv = 256(d)x128(n)
//    with swapped operands so Ft[d][n]/Vt[e][n] store directly (no transpose).
//    32 MFMAs per wave per K-step; acc = 32 f32x4 = 128 VGPRs.
//  - bm_gemm: Ft x Vt, split-K=2 partials, no atomics.  scale -> Ct.

typedef __bf16 bf16_t;
typedef __attribute__((ext_vector_type(8))) __bf16 bf16x8;
typedef __attribute__((ext_vector_type(4))) float f32x4;

#define MFMA_BF16 __builtin_amdgcn_mfma_f32_16x16x32_bf16

__device__ inline void async_ld16(const void* g, void* l) {
  __builtin_amdgcn_global_load_lds(
      (const __attribute__((address_space(1))) void*)g,
      (__attribute__((address_space(3))) void*)l, 16, 0, 0);
}

#define INV_D4 0.2102241038134287f  // 1 / 512^0.25

// ---------------- W transpose+convert: W[in][out] f32 -> Wt[out][in] bf16 ----
__global__ __launch_bounds__(256) void wt_kernel(
    const float* __restrict__ Wq, const float* __restrict__ Wk,
    const float* __restrict__ Wv, bf16_t* __restrict__ Wt) {
  const int z = blockIdx.z;
  const float* W = (z == 0) ? Wq : (z == 1) ? Wk : Wv;
  bf16_t* O = Wt + (size_t)z * 262144;
  __shared__ __align__(16) bf16_t tile[64 * 72];
  const int t = threadIdx.x;
  const int r = t >> 2;
  const int c4 = (t & 3) * 16;
  const int in0 = blockIdx.x * 64, out0 = blockIdx.y * 64;
  const float* src = W + (size_t)(in0 + r) * 512 + out0 + c4;
#pragma unroll
  for (int i = 0; i < 4; ++i) {
    float4 f = ((const float4*)src)[i];
    tile[(c4 + i * 4 + 0) * 72 + r] = (__bf16)f.x;
    tile[(c4 + i * 4 + 1) * 72 + r] = (__bf16)f.y;
    tile[(c4 + i * 4 + 2) * 72 + r] = (__bf16)f.z;
    tile[(c4 + i * 4 + 3) * 72 + r] = (__bf16)f.w;
  }
  __syncthreads();
  bf16x8* dst = (bf16x8*)(O + (size_t)(out0 + r) * 512 + in0 + c4);
  const bf16x8* s = (const bf16x8*)(tile + r * 72 + c4);
  dst[0] = s[0];
  dst[1] = s[1];
}

// ---------------- proj_q: Eq[n][d]=exp((Xq@Wq+b)/d4), 128x256 tiles ---------
// A = Xq rows (fp32, in-loop cvt w/ prefetch), B = Wq rows (async).
__global__ __launch_bounds__(256, 2) void proj_q(
    const float* __restrict__ Xq, const bf16_t* __restrict__ Wt,
    const float* __restrict__ bias, bf16_t* __restrict__ Eq,
    float* __restrict__ Sq) {
  __shared__ __align__(16) bf16_t Xs[4096];  // 128 rows x 32k, chunk-major
  __shared__ __align__(16) bf16_t Ws[8192];  // 256 rows x 32k, chunk-major

  const int t = threadIdx.x;
  const int lane = t & 63, w = t >> 6;
  const int quad = lane >> 4, l15 = lane & 15;
  const int m0 = blockIdx.x * 128;
  const int n0 = blockIdx.y * 256;
  const int m_off = (w & 1) * 64, n_off = (w >> 1) * 128;

  f32x4 acc[4][8];
  const f32x4 zero4 = {0.f, 0.f, 0.f, 0.f};
#pragma unroll
  for (int i = 0; i < 4; ++i)
#pragma unroll
    for (int j = 0; j < 8; ++j) acc[i][j] = zero4;

  const int ar = t >> 1;
  const int ac = (t & 1) * 16;
  const float* abase = Xq + (size_t)(m0 + ar) * 512 + ac;

  float4 f0 = ((const float4*)abase)[0];
  float4 f1 = ((const float4*)abase)[1];
  float4 f2 = ((const float4*)abase)[2];
  float4 f3 = ((const float4*)abase)[3];

  for (int ks = 0; ks < 16; ++ks) {
    bf16x8 p0, p1;
    p0[0] = (__bf16)f0.x; p0[1] = (__bf16)f0.y; p0[2] = (__bf16)f0.z; p0[3] = (__bf16)f0.w;
    p0[4] = (__bf16)f1.x; p0[5] = (__bf16)f1.y; p0[6] = (__bf16)f1.z; p0[7] = (__bf16)f1.w;
    p1[0] = (__bf16)f2.x; p1[1] = (__bf16)f2.y; p1[2] = (__bf16)f2.z; p1[3] = (__bf16)f2.w;
    p1[4] = (__bf16)f3.x; p1[5] = (__bf16)f3.y; p1[6] = (__bf16)f3.z; p1[7] = (__bf16)f3.w;
    ((bf16x8*)Xs)[(ac >> 3) * 128 + ar] = p0;
    ((bf16x8*)Xs)[((ac >> 3) + 1) * 128 + ar] = p1;

#pragma unroll
    for (int i = 0; i < 4; ++i) {
      const int j = w * 4 + i;
      const int k8 = j >> 2;
      const int r = ((j & 3) << 6) + lane;
      async_ld16(Wt + (size_t)(n0 + r) * 512 + ks * 32 + k8 * 8, Ws + j * 512);
    }
    __syncthreads();

    bf16x8 af[4], bfr[8];
#pragma unroll
    for (int mi = 0; mi < 4; ++mi)
      af[mi] = ((const bf16x8*)Xs)[quad * 128 + m_off + mi * 16 + l15];
#pragma unroll
    for (int ni = 0; ni < 8; ++ni)
      bfr[ni] = ((const bf16x8*)Ws)[quad * 256 + n_off + ni * 16 + l15];

    if (ks < 15) {
      const float4* p = (const float4*)(abase + (ks + 1) * 32);
      f0 = p[0]; f1 = p[1]; f2 = p[2]; f3 = p[3];
    }

#pragma unroll
    for (int mi = 0; mi < 4; ++mi)
#pragma unroll
      for (int ni = 0; ni < 8; ++ni)
        acc[mi][ni] = MFMA_BF16(af[mi], bfr[ni], acc[mi][ni], 0, 0, 0);
    __syncthreads();
  }

  const int b = m0 >> 12;
  float cs[8];
#pragma unroll
  for (int ni = 0; ni < 8; ++ni) cs[ni] = 0.f;
#pragma unroll
  for (int ni = 0; ni < 8; ++ni) {
    const int col = n0 + n_off + ni * 16 + l15;
    const float bv_ = bias[col];
#pragma unroll
    for (int mi = 0; mi < 4; ++mi)
#pragma unroll
      for (int r = 0; r < 4; ++r) {
        const int row = m0 + m_off + mi * 16 + quad * 4 + r;
        float v = __expf((acc[mi][ni][r] + bv_) * INV_D4);
        Eq[(size_t)row * 512 + col] = (bf16_t)v;
        cs[ni] += v;
      }
  }
#pragma unroll
  for (int ni = 0; ni < 8; ++ni) {
    cs[ni] += __shfl_xor(cs[ni], 16);
    cs[ni] += __shfl_xor(cs[ni], 32);
  }
  if (lane < 16) {
#pragma unroll
    for (int ni = 0; ni < 8; ++ni)
      atomicAdd(&Sq[b * 512 + n0 + n_off + ni * 16 + lane], cs[ni]);
  }
}

// ---------------- proj_kv: Ft/Vt[b][d][n], 256(d)x128(n) tiles --------------
// A = W rows (d, async), B = X rows (n, fp32 in-loop cvt) -> C already [d][n].
__global__ __launch_bounds__(256, 2) void proj_kv(
    const float* __restrict__ xk, const float* __restrict__ xv,
    const bf16_t* __restrict__ Wt, const float* __restrict__ bk,
    const float* __restrict__ bv, bf16_t* __restrict__ Ft,
    bf16_t* __restrict__ Vt) {
  const int z = blockIdx.z + 1;  // 1=K, 2=V
  const float* X = (z == 1) ? xk : xv;
  const float* bias = (z == 1) ? bk : bv;
  const bf16_t* W = Wt + (size_t)z * 262144;
  bf16_t* Out = (z == 1) ? Ft : Vt;
  const bool expm = (z == 1);

  __shared__ __align__(16) bf16_t Xs[4096];  // 128 n-rows x 32k
  __shared__ __align__(16) bf16_t Ws[8192];  // 256 d-rows x 32k

  const int t = threadIdx.x;
  const int lane = t & 63, w = t >> 6;
  const int quad = lane >> 4, l15 = lane & 15;
  const int ng = blockIdx.x * 128;  // global n over 32768
  const int w0 = blockIdx.y * 256;  // d tile
  const int m_off = (w & 1) * 128, n_off = (w >> 1) * 64;

  f32x4 acc[8][4];
  const f32x4 zero4 = {0.f, 0.f, 0.f, 0.f};
#pragma unroll
  for (int i = 0; i < 8; ++i)
#pragma unroll
    for (int j = 0; j < 4; ++j) acc[i][j] = zero4;

  const int br = t >> 1;
  const int bc = (t & 1) * 16;
  const float* bbase = X + (size_t)(ng + br) * 512 + bc;

  float4 f0 = ((const float4*)bbase)[0];
  float4 f1 = ((const float4*)bbase)[1];
  float4 f2 = ((const float4*)bbase)[2];
  float4 f3 = ((const float4*)bbase)[3];

  for (int ks = 0; ks < 16; ++ks) {
    bf16x8 p0, p1;
    p0[0] = (__bf16)f0.x; p0[1] = (__bf16)f0.y; p0[2] = (__bf16)f0.z; p0[3] = (__bf16)f0.w;
    p0[4] = (__bf16)f1.x; p0[5] = (__bf16)f1.y; p0[6] = (__bf16)f1.z; p0[7] = (__bf16)f1.w;
    p1[0] = (__bf16)f2.x; p1[1] = (__bf16)f2.y; p1[2] = (__bf16)f2.z; p1[3] = (__bf16)f2.w;
    p1[4] = (__bf16)f3.x; p1[5] = (__bf16)f3.y; p1[6] = (__bf16)f3.z; p1[7] = (__bf16)f3.w;
    ((bf16x8*)Xs)[(bc >> 3) * 128 + br] = p0;
    ((bf16x8*)Xs)[((bc >> 3) + 1) * 128 + br] = p1;

#pragma unroll
    for (int i = 0; i < 4; ++i) {
      const int j = w * 4 + i;
      const int k8 = j >> 2;
      const int r = ((j & 3) << 6) + lane;
      async_ld16(W + (size_t)(w0 + r) * 512 + ks * 32 + k8 * 8, Ws + j * 512);
    }
    __syncthreads();

    bf16x8 af[8], bfr[4];
#pragma unroll
    for (int mi = 0; mi < 8; ++mi)
      af[mi] = ((const bf16x8*)Ws)[quad * 256 + m_off + mi * 16 + l15];
#pragma unroll
    for (int ni = 0; ni < 4; ++ni)
      bfr[ni] = ((const bf16x8*)Xs)[quad * 128 + n_off + ni * 16 + l15];

    if (ks < 15) {
      const float4* p = (const float4*)(bbase + (ks + 1) * 32);
      f0 = p[0]; f1 = p[1]; f2 = p[2]; f3 = p[3];
    }

#pragma unroll
    for (int mi = 0; mi < 8; ++mi)
#pragma unroll
      for (int ni = 0; ni < 4; ++ni)
        acc[mi][ni] = MFMA_BF16(af[mi], bfr[ni], acc[mi][ni], 0, 0, 0);
    __syncthreads();
  }

  const int b = ng >> 12;
  const int nl0 = (ng & 4095) + n_off;
#pragma unroll
  for (int mi = 0; mi < 8; ++mi)
#pragma unroll
    for (int r = 0; r < 4; ++r) {
      const int d = w0 + m_off + mi * 16 + quad * 4 + r;
      const float bv_ = bias[d];
      bf16_t* rowp = Out + (size_t)b * 2097152 + (size_t)d * 4096 + nl0;
#pragma unroll
      for (int ni = 0; ni < 4; ++ni) {
        float v = acc[mi][ni][r] + bv_;
        if (expm) v = __expf(v * INV_D4);
        rowp[ni * 16 + l15] = (bf16_t)v;
      }
    }
}

// ---------------- Sk[b*512+d] = sum_n Ft[b][d][n] (row sums) ----------------
__global__ __launch_bounds__(256) void sk_kernel(const bf16_t* __restrict__ Ft,
                                                 float* __restrict__ Sk) {
  const int row = blockIdx.x * 4 + (threadIdx.x >> 6);
  const int lane = threadIdx.x & 63;
  const bf16x8* p = (const bf16x8*)(Ft + (size_t)row * 4096) + lane;
  float s = 0.f;
#pragma unroll
  for (int j = 0; j < 8; ++j) {
    bf16x8 v = p[j * 64];
#pragma unroll
    for (int e = 0; e < 8; ++e) s += (float)v[e];
  }
#pragma unroll
  for (int m = 1; m <= 32; m <<= 1) s += __shfl_xor(s, m);
  if (lane == 0) Sk[row] = s;
}

// ---------------- Bm GEMM: Bmp[s][b][d][e] = sum_{n in slice} Ft[d][n]Vt[e][n]
__global__ __launch_bounds__(256, 2) void bm_gemm(
    const bf16_t* __restrict__ Ft, const bf16_t* __restrict__ Vt,
    float* __restrict__ Bmp) {
  const int b = blockIdx.z >> 1;
  const int s = blockIdx.z & 1;
  const int d0 = blockIdx.x * 128;
  const int e0 = blockIdx.y * 128;
  const bf16_t* A = Ft + (size_t)b * 2097152;
  const bf16_t* B = Vt + (size_t)b * 2097152;
  float* out = Bmp + ((size_t)s * 8 + b) * 262144;

  __shared__ __align__(16) bf16_t As[4096];
  __shared__ __align__(16) bf16_t Bs[4096];

  const int t = threadIdx.x;
  const int lane = t & 63, w = t >> 6;
  const int quad = lane >> 4, l15 = lane & 15;
  const int m_off = (w & 1) * 64, n_off = (w >> 1) * 64;

  f32x4 acc[4][4];
  const f32x4 zero4 = {0.f, 0.f, 0.f, 0.f};
#pragma unroll
  for (int i = 0; i < 4; ++i)
#pragma unroll
    for (int j = 0; j < 4; ++j) acc[i][j] = zero4;

  for (int ks = 0; ks < 64; ++ks) {
    const int k0 = s * 2048 + ks * 32;
#pragma unroll
    for (int i = 0; i < 2; ++i) {
      const int j = w * 2 + i;
      const int k8 = j >> 1;
      const int r = ((j & 1) << 6) + lane;
      async_ld16(A + (size_t)(d0 + r) * 4096 + k0 + k8 * 8, As + j * 512);
      async_ld16(B + (size_t)(e0 + r) * 4096 + k0 + k8 * 8, Bs + j * 512);
    }
    __syncthreads();
    bf16x8 af[4], bfr[4];
#pragma unroll
    for (int mi = 0; mi < 4; ++mi)
      af[mi] = ((const bf16x8*)As)[quad * 128 + m_off + mi * 16 + l15];
#pragma unroll
    for (int ni = 0; ni < 4; ++ni)
      bfr[ni] = ((const bf16x8*)Bs)[quad * 128 + n_off + ni * 16 + l15];
#pragma unroll
    for (int mi = 0; mi < 4; ++mi)
#pragma unroll
      for (int ni = 0; ni < 4; ++ni)
        acc[mi][ni] = MFMA_BF16(af[mi], bfr[ni], acc[mi][ni], 0, 0, 0);
    __syncthreads();
  }

#pragma unroll
  for (int mi = 0; mi < 4; ++mi)
#pragma unroll
    for (int ni = 0; ni < 4; ++ni) {
      const int ecol = e0 + n_off + ni * 16 + l15;
#pragma unroll
      for (int r = 0; r < 4; ++r) {
        const int drow = d0 + m_off + mi * 16 + quad * 4 + r;
        out[(size_t)drow * 512 + ecol] = acc[mi][ni][r];
      }
    }
}

// ---------------- scale + reduce partials + transpose -----------------------
// Ct[b][e][d] = (Bmp0+Bmp1)[b][d][e] / (Sq[b][d]*Sk[b][d])
__global__ __launch_bounds__(256) void scale_kernel(
    const float* __restrict__ Bmp, const float* __restrict__ Sq,
    const float* __restrict__ Sk, bf16_t* __restrict__ Ct) {
  const int b = blockIdx.z;
  const int d0 = blockIdx.x * 64, e0 = blockIdx.y * 64;
  __shared__ __align__(16) bf16_t tile[64 * 72];
  const int t = threadIdx.x;
  const int r = t >> 2;
  const int c4 = (t & 3) * 16;
  const int d = d0 + r;
  const float f = 1.0f / (Sq[b * 512 + d] * Sk[b * 512 + d]);
  const float* p0 = Bmp + (size_t)b * 262144 + (size_t)d * 512 + e0 + c4;
  const float* p1 = p0 + 2097152;
#pragma unroll
  for (int i = 0; i < 4; ++i) {
    float4 v0 = ((const float4*)p0)[i];
    float4 v1 = ((const float4*)p1)[i];
    tile[(c4 + i * 4 + 0) * 72 + r] = (__bf16)((v0.x + v1.x) * f);
    tile[(c4 + i * 4 + 1) * 72 + r] = (__bf16)((v0.y + v1.y) * f);
    tile[(c4 + i * 4 + 2) * 72 + r] = (__bf16)((v0.z + v1.z) * f);
    tile[(c4 + i * 4 + 3) * 72 + r] = (__bf16)((v0.w + v1.w) * f);
  }
  __syncthreads();
  bf16x8* dst = (bf16x8*)(Ct + (size_t)b * 262144 + (size_t)(e0 + r) * 512 + d0 + c4);
  const bf16x8* s = (const bf16x8*)(tile + r * 72 + c4);
  dst[0] = s[0];
  dst[1] = s[1];
}

// ---------------- Z GEMM: Z[row,e]=sum_d Eq[row,d]*Ct[b][e][d], 128x256 -----
__global__ __launch_bounds__(256, 2) void z_gemm(
    const bf16_t* __restrict__ Eq, const bf16_t* __restrict__ Ct,
    float* __restrict__ out) {
  __shared__ __align__(16) bf16_t As[4096];  // Eq 128 rows
  __shared__ __align__(16) bf16_t Bs[8192];  // Ct 256 rows

  const int t = threadIdx.x;
  const int lane = t & 63, w = t >> 6;
  const int quad = lane >> 4, l15 = lane & 15;
  const int m0 = blockIdx.x * 128;
  const int n0 = blockIdx.y * 256;
  const int batch = m0 >> 12;
  const bf16_t* Bt = Ct + (size_t)batch * 262144;
  const int m_off = (w & 1) * 64, n_off = (w >> 1) * 128;

  f32x4 acc[4][8];
  const f32x4 zero4 = {0.f, 0.f, 0.f, 0.f};
#pragma unroll
  for (int i = 0; i < 4; ++i)
#pragma unroll
    for (int j = 0; j < 8; ++j) acc[i][j] = zero4;

  for (int ks = 0; ks < 16; ++ks) {
    const int k0 = ks * 32;
#pragma unroll
    for (int i = 0; i < 2; ++i) {
      const int j = w * 2 + i;
      const int k8 = j >> 1;
      const int r = ((j & 1) << 6) + lane;
      async_ld16(Eq + (size_t)(m0 + r) * 512 + k0 + k8 * 8, As + j * 512);
    }
#pragma unroll
    for (int i = 0; i < 4; ++i) {
      const int j = w * 4 + i;
      const int k8 = j >> 2;
      const int r = ((j & 3) << 6) + lane;
      async_ld16(Bt + (size_t)(n0 + r) * 512 + k0 + k8 * 8, Bs + j * 512);
    }
    __syncthreads();
    bf16x8 af[4], bfr[8];
#pragma unroll
    for (int mi = 0; mi < 4; ++mi)
      af[mi] = ((const bf16x8*)As)[quad * 128 + m_off + mi * 16 + l15];
#pragma unroll
    for (int ni = 0; ni < 8; ++ni)
      bfr[ni] = ((const bf16x8*)Bs)[quad * 256 + n_off + ni * 16 + l15];
#pragma unroll
    for (int mi = 0; mi < 4; ++mi)
#pragma unroll
      for (int ni = 0; ni < 8; ++ni)
        acc[mi][ni] = MFMA_BF16(af[mi], bfr[ni], acc[mi][ni], 0, 0, 0);
    __syncthreads();
  }

#pragma unroll
  for (int mi = 0; mi < 4; ++mi)
#pragma unroll
    for (int ni = 0; ni < 8; ++ni) {
      const int col = n0 + n_off + ni * 16 + l15;
#pragma unroll
      for (int r = 0; r < 4; ++r) {
        const int row = m0 + m_off + mi * 16 + quad * 4 + r;
        out[(size_t)row * 512 + col] = acc[mi][ni][r];
      }
    }
}

extern "C" void kernel_launch(void* const* d_in, const int* in_sizes, int n_in,
                              void* d_out, int out_size, void* d_ws,
                              size_t ws_size, hipStream_t stream) {
  const float* xq = (const float*)d_in[0];
  const float* xk = (const float*)d_in[1];
  const float* xv = (const float*)d_in[2];
  const float* Wq = (const float*)d_in[3];
  const float* bq = (const float*)d_in[4];
  const float* Wk = (const float*)d_in[5];
  const float* bk = (const float*)d_in[6];
  const float* Wv = (const float*)d_in[7];
  const float* bv = (const float*)d_in[8];
  float* out = (float*)d_out;

  char* ws = (char*)d_ws;
  bf16_t* Eq = (bf16_t*)(ws + 0);           // 8x4096x512 bf16  33,554,432 B
  bf16_t* Ft = (bf16_t*)(ws + 33554432);    // 8x512x4096 bf16 (F transposed)
  bf16_t* Vt = (bf16_t*)(ws + 67108864);    // 8x512x4096 bf16 (V transposed)
  float* Bmp = (float*)(ws + 100663296);    // 2 x 8x512x512 f32 split-K partials
  bf16_t* Wt = (bf16_t*)(ws + 117440512);   // 3x512x512 bf16
  float* Sq = (float*)(ws + 119013376);     // 8x512 f32
  float* Sk = (float*)(ws + 119029760);     // 8x512 f32; end = 119,046,144
  bf16_t* Ct = (bf16_t*)(ws + 33554432);    // aliases Ft (dead after bm_gemm)

  hipMemsetAsync(Sq, 0, 16384, stream);  // Sq atomic target only

  wt_kernel<<<dim3(8, 8, 3), 256, 0, stream>>>(Wq, Wk, Wv, Wt);
  proj_q<<<dim3(256, 2), 256, 0, stream>>>(xq, Wt, bq, Eq, Sq);
  proj_kv<<<dim3(256, 2, 2), 256, 0, stream>>>(xk, xv, Wt, bk, bv, Ft, Vt);
  sk_kernel<<<dim3(1024), 256, 0, stream>>>(Ft, Sk);
  bm_gemm<<<dim3(4, 4, 16), 256, 0, stream>>>(Ft, Vt, Bmp);
  scale_kernel<<<dim3(8, 8, 8), 256, 0, stream>>>(Bmp, Sq, Sk, Ct);
  z_gemm<<<dim3(256, 2), 256, 0, stream>>>(Eq, Ct, out);
}